// Round 1
// 8461.848 us; speedup vs baseline: 1.1405x; 1.1405x over previous
//
#include <hip/hip_runtime.h>

typedef unsigned short u16;
typedef unsigned int u32;
using short8  = __attribute__((ext_vector_type(8))) short;
using floatx4 = __attribute__((ext_vector_type(4))) float;

#define BATCH 256
#define SEQ   256
#define INSZ  128
#define ZS    1026
#define NBLK  256
#define MT    64      // rows per block
#define SASTR 136     // sA row stride (bf16) padded
#define SCSTR 68      // sC row stride (f32) padded

#define AL_RLX __ATOMIC_RELAXED
#define AL_REL __ATOMIC_RELEASE
#define SC_AGT __HIP_MEMORY_SCOPE_AGENT

__device__ __forceinline__ u16 f2bf(float f) {
    union { float f; unsigned u; } v; v.f = f;
    unsigned r = v.u + 0x7fffu + ((v.u >> 16) & 1u);
    return (u16)(r >> 16);
}
__device__ __forceinline__ u32 pack2(float a, float b) {
    return (u32)f2bf(a) | ((u32)f2bf(b) << 16);
}
__device__ __forceinline__ float sigf(float x)   { return 1.f / (1.f + __expf(-x)); }
__device__ __forceinline__ float tanhf_(float x) { return 1.f - 2.f / (__expf(2.f * x) + 1.f); }

// coherent (L2-bypass) dword ops — the ONLY way Abuf/D are touched after setup
__device__ __forceinline__ u32 cload(const u32* p) {
    return __hip_atomic_load(p, AL_RLX, SC_AGT);
}
__device__ __forceinline__ void cstore(u32* p, u32 v) {
    __hip_atomic_store(p, v, AL_RLX, SC_AGT);
}

__global__ void __launch_bounds__(256, 1) lstm_fused(
    const float* __restrict__ rnn, const float* __restrict__ tau,
    const float* __restrict__ z0,  const float* __restrict__ cz0,
    const float* __restrict__ WUw, const float* __restrict__ WUb,
    const float* __restrict__ aw,  const float* __restrict__ ab,
    const float* __restrict__ hw,  const float* __restrict__ hb,
    float* __restrict__ out,
    u16* __restrict__ Wp, u32* __restrict__ Abuf32, float* __restrict__ D,
    float* __restrict__ bp, float* __restrict__ wxp,
    unsigned* __restrict__ bar_cnt, unsigned* __restrict__ bar_gen,
    unsigned* __restrict__ barX, unsigned* __restrict__ barM,
    unsigned* __restrict__ barG)
{
    __shared__ __align__(16) char lds[2 * MT * SASTR * 2];   // sA | sB (34,816 B)
    __shared__ float sX[128];

    u16* sA = (u16*)lds;
    u16* sB = (u16*)(lds + MT * SASTR * 2);
    float* sC = (float*)lds;                    // reuse sA region after GEMM
    float* sH = (float*)(lds + MT * SASTR * 2); // reuse sB region in pointwise

    const int tid = threadIdx.x;
    const int bid = blockIdx.x;
    const int gtid = bid * 256 + tid;

    // block decomposition: xcd-partitioned W locality
    const int xcd = bid & 7, q = (bid >> 3) & 7, mt = bid >> 6;
    const int jt = xcd * 8 + q;          // 0..63 (16 j's each)
    const int m0 = mt * 64;
    const int j0 = jt * 16;
    const bool writer = ((bid & 63) == 0);   // jt==0: one per mtile

    const int lane = tid & 63, wid = tid >> 6;
    const int l15 = lane & 15, quad = lane >> 4;
    const int wm = (wid & 1) * 32, wn = (wid >> 1) * 32;

    // ---------------- setup ----------------
    // W repack: Wp[jt][r][k], r = g*16+jj <-> n = g*1024 + jt*16 + jj
    {
        const int jts = bid >> 2, q4 = bid & 3;
        for (int r = q4 * 16; r < q4 * 16 + 16; ++r) {
            int n = (r >> 4) * 1024 + jts * 16 + (r & 15);
            const float* src = WUw + (size_t)n * 1154 + 2;
            u16* dst = Wp + (size_t)jts * 73728 + r * 1152;
            for (int k = tid; k < 1152; k += 256) dst[k] = f2bf(src[k]);
        }
    }
    // bias / x-weight repack (r-order)
    if (gtid < 4096) {
        int jte = gtid >> 6, r = gtid & 63;
        int n = (r >> 4) * 1024 + jte * 16 + (r & 15);
        bp[gtid] = WUb[n];
        wxp[2 * gtid] = WUw[(size_t)n * 1154];
        wxp[2 * gtid + 1] = WUw[(size_t)n * 1154 + 1];
    }
    // Abuf init: row = bid, 512 dwords of packed h0 (u now read straight from rnn)
    {
        int m = bid;
        for (int c = tid; c < 512; c += 256) {
            float v0 = z0[m * ZS + 2 + 2 * c];
            float v1 = z0[m * ZS + 3 + 2 * c];
            Abuf32[m * 512 + c] = pack2(v0, v1);   // plain; flushed by setup fence
        }
    }
    if (gtid < 3072) D[gtid] = 0.f;

    // c-state in registers for the whole sequence: cell i -> (m=(tid>>4)+16i, jj=tid&15)
    float cr[4];
#pragma unroll
    for (int i = 0; i < 4; ++i) {
        int m = (tid >> 4) + 16 * i, jj = tid & 15;
        cr[i] = cz0[(m0 + m) * ZS + 2 + j0 + jj];
    }
    // x-state (threads 0..63 hold row m0+tid)
    float xp0 = 0.f, xp1 = 0.f;
    if (tid < 64) { xp0 = z0[(m0 + tid) * ZS + 0]; xp1 = z0[(m0 + tid) * ZS + 1]; }

    // setup barrier WITH full fences (flush plain-written Wp/Abuf/bp to coherence point)
    __syncthreads();
    if (tid == 0) {
        __threadfence();
        unsigned g = __hip_atomic_load(bar_gen, AL_RLX, SC_AGT);
        unsigned a = __hip_atomic_fetch_add(bar_cnt, 1u, __ATOMIC_ACQ_REL, SC_AGT);
        if (a == NBLK - 1) {
            __hip_atomic_store(bar_cnt, 0u, AL_RLX, SC_AGT);
            __hip_atomic_fetch_add(bar_gen, 1u, AL_REL, SC_AGT);
        } else {
            while (__hip_atomic_load(bar_gen, __ATOMIC_ACQUIRE, SC_AGT) == g)
                __builtin_amdgcn_s_sleep(2);
        }
        __threadfence();
    }
    __syncthreads();

    const u16* WpT = Wp + (size_t)jt * 73728;
    float* zf  = out + (size_t)BATCH * SEQ * ZS;
    float* czf = zf + (size_t)BATCH * ZS;

    // per-mt tree-barrier pointers (leaf: 8 blocks of same (mt,xcd); combine: 8 xcds)
    unsigned* bcx = barX + (((mt << 3) | xcd) * 64);
    unsigned* bcm = barM + mt * 64;
    unsigned* bgg = barG + mt * 64;

    // chunk-load helpers (2-deep register prefetch sets)
#define ISSUE_A(AR, CH) do { _Pragma("unroll") \
    for (int i = 0; i < 16; ++i) { int d = tid + i * 256; \
        AR[i] = cload(Abuf32 + (m0 + (d >> 6)) * 512 + ((CH) - 1) * 64 + (d & 63)); } } while (0)
#define ISSUE_W(WR, CH) do { _Pragma("unroll") \
    for (int i = 0; i < 4; ++i) { int s = tid + i * 256; \
        WR[i] = *(const uint4*)(WpT + (size_t)(s >> 4) * 1152 + (CH) * 128 + (s & 15) * 8); } } while (0)
#define WRITE_LDS(AR, WR) do { _Pragma("unroll") \
    for (int i = 0; i < 16; ++i) { int d = tid + i * 256; \
        *(u32*)&sA[(d >> 6) * SASTR + (d & 63) * 2] = AR[i]; } \
    _Pragma("unroll") \
    for (int i = 0; i < 4; ++i) { int s = tid + i * 256; \
        *(uint4*)&sB[(s >> 4) * SASTR + (s & 15) * 8] = WR[i]; } } while (0)
#define MFMA_PHASE() do { _Pragma("unroll") \
    for (int kk = 0; kk < 4; ++kk) { \
        short8 af[2], bf[2]; \
        _Pragma("unroll") \
        for (int i = 0; i < 2; ++i) \
            af[i] = *(const short8*)&sA[(wm + i * 16 + l15) * SASTR + kk * 32 + quad * 8]; \
        _Pragma("unroll") \
        for (int i = 0; i < 2; ++i) \
            bf[i] = *(const short8*)&sB[(wn + i * 16 + l15) * SASTR + kk * 32 + quad * 8]; \
        _Pragma("unroll") \
        for (int i = 0; i < 2; ++i) \
            _Pragma("unroll") \
            for (int j = 0; j < 2; ++j) \
                acc[i][j] = __builtin_amdgcn_mfma_f32_16x16x32_bf16(af[i], bf[j], acc[i][j], 0, 0, 0); \
    } } while (0)

    for (int t = 0; t < SEQ; ++t) {
        // ---------- issue all long-latency loads up front ----------
        float d0 = 0.f, d1 = 0.f, d2 = 0.f, d3 = 0.f, ta = 0.f;
        if (tid < 64 && t > 0) {
            const float* Dp = D + ((t - 1) % 3) * 1024 + (m0 + tid) * 4;
            d0 = __hip_atomic_load(Dp + 0, AL_RLX, SC_AGT);
            d1 = __hip_atomic_load(Dp + 1, AL_RLX, SC_AGT);
            d2 = __hip_atomic_load(Dp + 2, AL_RLX, SC_AGT);
            d3 = __hip_atomic_load(Dp + 3, AL_RLX, SC_AGT);
            ta = tau[(m0 + tid) * SEQ + (t - 1)];
        }
        // chunk 0: u_t straight from rnn (plain, L2/L3-cached, read-only)
        float2 u2[16];
#pragma unroll
        for (int i = 0; i < 16; ++i) {
            int d = tid + i * 256;
            u2[i] = *(const float2*)(rnn + ((size_t)(m0 + (d >> 6)) * SEQ + t) * INSZ + 2 * (d & 63));
        }
        uint4 wR0[4];
#pragma unroll
        for (int i = 0; i < 4; ++i) {
            int s = tid + i * 256;
            wR0[i] = *(const uint4*)(WpT + (size_t)(s >> 4) * 1152 + (s & 15) * 8);
        }
        u32  aRA[16], aRB[16];
        uint4 wRA[4], wRB[4];
        ISSUE_A(aRA, 1); ISSUE_W(wRA, 1);

        // writer zeroes D[(t+1)%3] (reused 2 steps from now)
        if (writer) {
            float* Dz = D + ((t + 1) % 3) * 1024 + m0 * 4;
            __hip_atomic_store(Dz + tid, 0.f, AL_RLX, SC_AGT);
        }

        // ---------- phase X (overlapped with chunk-load flight) ----------
        if (tid < 64) {
            int mg = m0 + tid;
            if (t == 0) {
                sX[tid * 2] = xp0; sX[tid * 2 + 1] = xp1;
            } else {
                float al0 = sigf(d0 + ab[0]), al1 = sigf(d1 + ab[1]);
                float hx0 = d2 + hb[0], hx1 = d3 + hb[1];
                float xm0 = (1.f + 1.5f * ta) * xp0 - 1.5f * ta * xp1;
                float xm1 = (ta * (1.f / 1.5f)) * xp0 + xp1;
                float xn0 = al0 * xm0 + (1.f - al0) * hx0;
                float xn1 = al1 * xm1 + (1.f - al1) * hx1;
                xp0 = xn0; xp1 = xn1;
                sX[tid * 2] = xn0; sX[tid * 2 + 1] = xn1;
                if (writer) {
                    float* o = out + ((size_t)mg * SEQ + (t - 1)) * ZS;
                    o[0] = xn0; o[1] = xn1;
                }
            }
        }

        // ---------- GEMM: C(64x64) = A(64x1152) * Wp_tile(64x1152)^T ----------
        floatx4 acc[2][2];
        floatx4 z4 = {0.f, 0.f, 0.f, 0.f};
        acc[0][0] = z4; acc[0][1] = z4; acc[1][0] = z4; acc[1][1] = z4;

        // chunk 0 (u): pack f32->bf16 into LDS
#pragma unroll
        for (int i = 0; i < 16; ++i) {
            int d = tid + i * 256;
            *(u32*)&sA[(d >> 6) * SASTR + (d & 63) * 2] = pack2(u2[i].x, u2[i].y);
        }
#pragma unroll
        for (int i = 0; i < 4; ++i) {
            int s = tid + i * 256;
            *(uint4*)&sB[(s >> 4) * SASTR + (s & 15) * 8] = wR0[i];
        }
        __syncthreads();
        ISSUE_A(aRB, 2); ISSUE_W(wRB, 2);
        MFMA_PHASE();
        __syncthreads();

#pragma unroll
        for (int c = 1; c <= 8; c += 2) {
            WRITE_LDS(aRA, wRA);
            __syncthreads();
            if (c + 2 <= 8) { ISSUE_A(aRA, c + 2); ISSUE_W(wRA, c + 2); }
            MFMA_PHASE();
            __syncthreads();
            WRITE_LDS(aRB, wRB);
            __syncthreads();
            if (c + 3 <= 8) { ISSUE_A(aRB, c + 3); ISSUE_W(wRB, c + 3); }
            MFMA_PHASE();
            __syncthreads();
        }

        // ---------- exchange C through LDS (gates split across waves) ----------
#pragma unroll
        for (int i = 0; i < 2; ++i)
#pragma unroll
            for (int j = 0; j < 2; ++j) {
                int row = wm + i * 16 + quad * 4, col = wn + j * 16 + l15;
#pragma unroll
                for (int rr = 0; rr < 4; ++rr)
                    sC[(row + rr) * SCSTR + col] = acc[i][j][rr];
            }
        __syncthreads();

        // ---------- pointwise: cell i -> (m=(tid>>4)+16i, jj=tid&15) ----------
        float hv[4];
        float p0 = 0.f, p1 = 0.f, p2 = 0.f, p3 = 0.f;
        {
            float sx0, sx1;
#pragma unroll
            for (int i = 0; i < 4; ++i) {
                int m = (tid >> 4) + 16 * i, jj = tid & 15;
                sx0 = sX[m * 2]; sx1 = sX[m * 2 + 1];
                float gi = bp[jt * 64 + 0 * 16 + jj] + wxp[(jt * 64 + 0 * 16 + jj) * 2] * sx0 + wxp[(jt * 64 + 0 * 16 + jj) * 2 + 1] * sx1 + sC[m * SCSTR + 0 * 16 + jj];
                float gf = bp[jt * 64 + 1 * 16 + jj] + wxp[(jt * 64 + 1 * 16 + jj) * 2] * sx0 + wxp[(jt * 64 + 1 * 16 + jj) * 2 + 1] * sx1 + sC[m * SCSTR + 1 * 16 + jj];
                float gg = bp[jt * 64 + 2 * 16 + jj] + wxp[(jt * 64 + 2 * 16 + jj) * 2] * sx0 + wxp[(jt * 64 + 2 * 16 + jj) * 2 + 1] * sx1 + sC[m * SCSTR + 2 * 16 + jj];
                float go = bp[jt * 64 + 3 * 16 + jj] + wxp[(jt * 64 + 3 * 16 + jj) * 2] * sx0 + wxp[(jt * 64 + 3 * 16 + jj) * 2 + 1] * sx1 + sC[m * SCSTR + 3 * 16 + jj];
                float cn = sigf(gf) * cr[i] + sigf(gi) * tanhf_(gg);
                float hn = sigf(go) * tanhf_(cn);
                cr[i] = cn;
                hv[i] = hn;
                int jgl = j0 + jj, mg = m0 + m;
                out[((size_t)mg * SEQ + t) * ZS + 2 + jgl] = hn;
                if (t == SEQ - 1) { zf[mg * ZS + 2 + jgl] = hn; czf[mg * ZS + 2 + jgl] = cn; }
                p0 = hn * aw[jgl];        p1 = hn * aw[1024 + jgl];
                p2 = hn * hw[jgl];        p3 = hn * hw[1024 + jgl];
                // reduce over the 16 jj-lanes (contiguous within wave)
#pragma unroll
                for (int o = 8; o > 0; o >>= 1) {
                    p0 += __shfl_down(p0, o, 16); p1 += __shfl_down(p1, o, 16);
                    p2 += __shfl_down(p2, o, 16); p3 += __shfl_down(p3, o, 16);
                }
                if ((tid & 15) == 0) {
                    float* Dp = D + (t % 3) * 1024 + mg * 4;
                    __hip_atomic_fetch_add(Dp + 0, p0, AL_RLX, SC_AGT);
                    __hip_atomic_fetch_add(Dp + 1, p1, AL_RLX, SC_AGT);
                    __hip_atomic_fetch_add(Dp + 2, p2, AL_RLX, SC_AGT);
                    __hip_atomic_fetch_add(Dp + 3, p3, AL_RLX, SC_AGT);
                }
            }
        }
        // h -> Abuf (bf16, coherent): exchange pairs through sH[jj*65+m]
#pragma unroll
        for (int i = 0; i < 4; ++i) {
            int m = (tid >> 4) + 16 * i, jj = tid & 15;
            sH[jj * 65 + m] = hv[i];
        }
        __syncthreads();
#pragma unroll
        for (int i = 0; i < 2; ++i) {
            int dd = tid + i * 256;
            int m = dd >> 3, jp = dd & 7;
            u32 v = pack2(sH[(2 * jp) * 65 + m], sH[(2 * jp + 1) * 65 + m]);
            cstore(Abuf32 + (m0 + m) * 512 + jt * 8 + jp, v);
        }

        // ---------- per-mt-group tree barrier (8-way leaf + 8-way combine) ----------
        // release on arrive; no acquire needed: all cross-step reads are coherent ops
        __syncthreads();
        if (tid == 0) {
            unsigned g = __hip_atomic_load(bgg, AL_RLX, SC_AGT);
            unsigned a = __hip_atomic_fetch_add(bcx, 1u, AL_REL, SC_AGT);
            if (a == 7u) {
                __hip_atomic_store(bcx, 0u, AL_RLX, SC_AGT);
                unsigned b = __hip_atomic_fetch_add(bcm, 1u, __ATOMIC_ACQ_REL, SC_AGT);
                if (b == 7u) {
                    __hip_atomic_store(bcm, 0u, AL_RLX, SC_AGT);
                    __hip_atomic_fetch_add(bgg, 1u, AL_REL, SC_AGT);
                }
            }
            while (__hip_atomic_load(bgg, AL_RLX, SC_AGT) == g)
                __builtin_amdgcn_s_sleep(2);
        }
        __syncthreads();
    }

    // ---------- final x-update (t = SEQ) + frozen cz columns ----------
    if (tid < 64) {
        int mg = m0 + tid;
        const float* Dp = D + ((SEQ - 1) % 3) * 1024 + mg * 4;
        float s0 = __hip_atomic_load(Dp + 0, AL_RLX, SC_AGT);
        float s1 = __hip_atomic_load(Dp + 1, AL_RLX, SC_AGT);
        float s2 = __hip_atomic_load(Dp + 2, AL_RLX, SC_AGT);
        float s3 = __hip_atomic_load(Dp + 3, AL_RLX, SC_AGT);
        float al0 = sigf(s0 + ab[0]), al1 = sigf(s1 + ab[1]);
        float hx0 = s2 + hb[0], hx1 = s3 + hb[1];
        float ta = tau[mg * SEQ + (SEQ - 1)];
        float xm0 = (1.f + 1.5f * ta) * xp0 - 1.5f * ta * xp1;
        float xm1 = (ta * (1.f / 1.5f)) * xp0 + xp1;
        float xn0 = al0 * xm0 + (1.f - al0) * hx0;
        float xn1 = al1 * xm1 + (1.f - al1) * hx1;
        if (writer) {
            float* o = out + ((size_t)mg * SEQ + (SEQ - 1)) * ZS;
            o[0] = xn0; o[1] = xn1;
            zf[mg * ZS + 0] = xn0; zf[mg * ZS + 1] = xn1;
            czf[mg * ZS + 0] = cz0[mg * ZS + 0];
            czf[mg * ZS + 1] = cz0[mg * ZS + 1];
        }
    }
#undef ISSUE_A
#undef ISSUE_W
#undef WRITE_LDS
#undef MFMA_PHASE
}

extern "C" void kernel_launch(void* const* d_in, const int* in_sizes, int n_in,
                              void* d_out, int out_size, void* d_ws, size_t ws_size,
                              hipStream_t stream) {
    const float* rnn = (const float*)d_in[0];
    const float* tau = (const float*)d_in[1];
    const float* z0  = (const float*)d_in[2];
    const float* cz0 = (const float*)d_in[3];
    const float* WUw = (const float*)d_in[4];
    const float* WUb = (const float*)d_in[5];
    const float* aw  = (const float*)d_in[6];
    const float* ab  = (const float*)d_in[7];
    const float* hw  = (const float*)d_in[8];
    const float* hb  = (const float*)d_in[9];
    float* out = (float*)d_out;

    char* ws = (char*)d_ws;
    size_t off = 0;
    auto alloc = [&](size_t bytes) {
        void* p = ws + off;
        off += (bytes + 255) & ~(size_t)255;
        return p;
    };
    u16*   Wp     = (u16*)alloc((size_t)64 * 64 * 1152 * 2);   // 9.44 MB, jt-major
    u32*   Abuf32 = (u32*)alloc((size_t)BATCH * 512 * 4);      // 0.5 MB (h only)
    float* D      = (float*)alloc((size_t)3 * BATCH * 4 * 4);  // 12 KB
    float* bp     = (float*)alloc((size_t)4096 * 4);
    float* wxp    = (float*)alloc((size_t)8192 * 4);
    unsigned* bar_cnt = (unsigned*)alloc(256);
    unsigned* bar_gen = (unsigned*)alloc(256);
    unsigned* barX    = (unsigned*)alloc(32 * 64 * 4);   // 4mt x 8xcd, 256B stride
    unsigned* barM    = (unsigned*)alloc(4 * 64 * 4);    // per-mt combine
    unsigned* barG    = (unsigned*)alloc(4 * 64 * 4);    // per-mt generation

    // zero all barrier state in one contiguous memset (allocs are contiguous)
    hipMemsetAsync(bar_cnt, 0, 256 + 256 + 32 * 64 * 4 + 4 * 64 * 4 + 4 * 64 * 4, stream);

    hipLaunchKernelGGL(lstm_fused, dim3(NBLK), dim3(256), 0, stream,
                       rnn, tau, z0, cz0, WUw, WUb, aw, ab, hw, hb,
                       out, Wp, Abuf32, D, bp, wxp, bar_cnt, bar_gen,
                       barX, barM, barG);
}

// Round 3
// 5503.187 us; speedup vs baseline: 1.7536x; 1.5376x over previous
//
#include <hip/hip_runtime.h>

typedef unsigned short u16;
typedef unsigned int u32;
using short8  = __attribute__((ext_vector_type(8))) short;
using floatx4 = __attribute__((ext_vector_type(4))) float;
using f32x4   = floatx4;
using u32x4   = __attribute__((ext_vector_type(4))) u32;

#define BATCH 256
#define SEQ   256
#define INSZ  128
#define ZS    1026
#define NBLK  256
#define MT    64      // rows per block
#define SASTR 136     // sA row stride (bf16) padded
#define SCSTR 68      // sC row stride (f32) padded

#define AL_RLX __ATOMIC_RELAXED
#define AL_REL __ATOMIC_RELEASE
#define SC_AGT __HIP_MEMORY_SCOPE_AGENT

__device__ __forceinline__ u16 f2bf(float f) {
    union { float f; unsigned u; } v; v.f = f;
    unsigned r = v.u + 0x7fffu + ((v.u >> 16) & 1u);
    return (u16)(r >> 16);
}
__device__ __forceinline__ u32 pack2(float a, float b) {
    return (u32)f2bf(a) | ((u32)f2bf(b) << 16);
}
__device__ __forceinline__ float sigf(float x)   { return 1.f / (1.f + __expf(-x)); }
__device__ __forceinline__ float tanhf_(float x) { return 1.f - 2.f / (__expf(2.f * x) + 1.f); }

__device__ __forceinline__ void cstore(u32* p, u32 v) {
    __hip_atomic_store(p, v, AL_RLX, SC_AGT);
}

// ---- inline-asm loads: issue only; completion tracked by hand-counted vmcnt ----
__device__ __forceinline__ void gl4_sc1(u32x4& d, const void* p) {
    asm volatile("global_load_dwordx4 %0, %1, off sc1" : "=v"(d) : "v"(p) : "memory");
}
__device__ __forceinline__ void gl4(u32x4& d, const void* p) {
    asm volatile("global_load_dwordx4 %0, %1, off" : "=v"(d) : "v"(p) : "memory");
}
__device__ __forceinline__ void gl4f(f32x4& d, const void* p) {
    asm volatile("global_load_dwordx4 %0, %1, off" : "=v"(d) : "v"(p) : "memory");
}
__device__ __forceinline__ void gl4f_sc1(f32x4& d, const void* p) {
    asm volatile("global_load_dwordx4 %0, %1, off sc1" : "=v"(d) : "v"(p) : "memory");
}
__device__ __forceinline__ void gl1f(float& d, const void* p) {
    asm volatile("global_load_dword %0, %1, off" : "=v"(d) : "v"(p) : "memory");
}
#define VMW(N) asm volatile("s_waitcnt vmcnt(" N ")" ::: "memory")
#define LG0    asm volatile("s_waitcnt lgkmcnt(0)" ::: "memory")
#define BARR   asm volatile("s_barrier" ::: "memory")
#define SCH0   __builtin_amdgcn_sched_barrier(0)

__global__ void __launch_bounds__(256, 1) lstm_fused(
    const float* __restrict__ rnn, const float* __restrict__ tau,
    const float* __restrict__ z0,  const float* __restrict__ cz0,
    const float* __restrict__ WUw, const float* __restrict__ WUb,
    const float* __restrict__ aw,  const float* __restrict__ ab,
    const float* __restrict__ hw,  const float* __restrict__ hb,
    float* __restrict__ out,
    u16* __restrict__ Wp, u32* __restrict__ Abuf32, float* __restrict__ D,
    float* __restrict__ bp, float* __restrict__ wxp,
    unsigned* __restrict__ bar_cnt, unsigned* __restrict__ bar_gen,
    unsigned* __restrict__ barX, unsigned* __restrict__ barM,
    unsigned* __restrict__ barG)
{
    __shared__ __align__(16) char lds[2 * MT * SASTR * 2];   // sA | sB (34,816 B)
    __shared__ float sX[128];

    u16* sA = (u16*)lds;
    u16* sB = (u16*)(lds + MT * SASTR * 2);
    float* sC = (float*)lds;                    // reuse sA region after GEMM
    float* sH = (float*)(lds + MT * SASTR * 2); // reuse sB region in pointwise

    const int tid = threadIdx.x;
    const int bid = blockIdx.x;
    const int gtid = bid * 256 + tid;

    const int xcd = bid & 7, q = (bid >> 3) & 7, mt = bid >> 6;
    const int jt = xcd * 8 + q;          // 0..63 (16 j's each)
    const int m0 = mt * 64;
    const int j0 = jt * 16;
    const bool writer = ((bid & 63) == 0);

    const int lane = tid & 63, wid = tid >> 6;
    const int l15 = lane & 15, quad = lane >> 4;
    const int wm = (wid & 1) * 32, wn = (wid >> 1) * 32;

    // ---------------- setup ----------------
    {
        const int jts = bid >> 2, q4 = bid & 3;
        for (int r = q4 * 16; r < q4 * 16 + 16; ++r) {
            int n = (r >> 4) * 1024 + jts * 16 + (r & 15);
            const float* src = WUw + (size_t)n * 1154 + 2;
            u16* dst = Wp + (size_t)jts * 73728 + r * 1152;
            for (int k = tid; k < 1152; k += 256) dst[k] = f2bf(src[k]);
        }
    }
    if (gtid < 4096) {
        int jte = gtid >> 6, r = gtid & 63;
        int n = (r >> 4) * 1024 + jte * 16 + (r & 15);
        bp[gtid] = WUb[n];
        wxp[2 * gtid] = WUw[(size_t)n * 1154];
        wxp[2 * gtid + 1] = WUw[(size_t)n * 1154 + 1];
    }
    {
        int m = bid;
        for (int c = tid; c < 512; c += 256) {
            float v0 = z0[m * ZS + 2 + 2 * c];
            float v1 = z0[m * ZS + 3 + 2 * c];
            Abuf32[m * 512 + c] = pack2(v0, v1);
        }
    }
    if (gtid < 3072) D[gtid] = 0.f;

    float cr[4];
#pragma unroll
    for (int i = 0; i < 4; ++i) {
        int m = (tid >> 4) + 16 * i, jj_ = tid & 15;
        cr[i] = cz0[(m0 + m) * ZS + 2 + j0 + jj_];
    }
    float xp0 = 0.f, xp1 = 0.f;
    if (tid < 64) { xp0 = z0[(m0 + tid) * ZS + 0]; xp1 = z0[(m0 + tid) * ZS + 1]; }

    // setup barrier WITH full fences
    __syncthreads();
    if (tid == 0) {
        __threadfence();
        unsigned g = __hip_atomic_load(bar_gen, AL_RLX, SC_AGT);
        unsigned a = __hip_atomic_fetch_add(bar_cnt, 1u, __ATOMIC_ACQ_REL, SC_AGT);
        if (a == NBLK - 1) {
            __hip_atomic_store(bar_cnt, 0u, AL_RLX, SC_AGT);
            __hip_atomic_fetch_add(bar_gen, 1u, AL_REL, SC_AGT);
        } else {
            while (__hip_atomic_load(bar_gen, __ATOMIC_ACQUIRE, SC_AGT) == g)
                __builtin_amdgcn_s_sleep(2);
        }
        __threadfence();
    }
    __syncthreads();

    const u16* WpT = Wp + (size_t)jt * 73728;
    float* zf  = out + (size_t)BATCH * SEQ * ZS;
    float* czf = zf + (size_t)BATCH * ZS;

    unsigned* bcx = barX + (((mt << 3) | xcd) * 64);
    unsigned* bcm = barM + mt * 64;
    unsigned* bgg = barG + mt * 64;

    // ---- hoisted t-invariant values ----
    const float ab0 = ab[0], ab1 = ab[1], hb0 = hb[0], hb1 = hb[1];
    const int jj = tid & 15;
    float bpv[4], wxa[4], wxb[4];
#pragma unroll
    for (int g = 0; g < 4; ++g) {
        int n = jt * 64 + g * 16 + jj;
        bpv[g] = bp[n]; wxa[g] = wxp[2 * n]; wxb[g] = wxp[2 * n + 1];
    }
    const float aw0 = aw[j0 + jj], aw1 = aw[1024 + j0 + jj];
    const float hw0 = hw[j0 + jj], hw1 = hw[1024 + j0 + jj];

// batch issue: A-chunk CH (1..8, h-part) as 4x dwordx4 sc1; W-chunk CH as 4x dwordx4 plain
#define ISSUE_AW(AS, WS, CH) do { _Pragma("unroll") \
    for (int i = 0; i < 4; ++i) { int s = tid + i * 256; \
        gl4_sc1(AS[i], Abuf32 + (size_t)(m0 + (s >> 4)) * 512 + ((CH) - 1) * 64 + (s & 15) * 4); } \
    _Pragma("unroll") \
    for (int i = 0; i < 4; ++i) { int s = tid + i * 256; \
        gl4(WS[i], WpT + (size_t)(s >> 4) * 1152 + (CH) * 128 + (s & 15) * 8); } } while (0)

#define WRITE_AW(AS, WS) do { _Pragma("unroll") \
    for (int i = 0; i < 4; ++i) { int s = tid + i * 256; \
        *(u32x4*)((char*)sA + (s >> 4) * (SASTR * 2) + (s & 15) * 16) = AS[i]; } \
    _Pragma("unroll") \
    for (int i = 0; i < 4; ++i) { int s = tid + i * 256; \
        *(u32x4*)((char*)sB + (s >> 4) * (SASTR * 2) + (s & 15) * 16) = WS[i]; } } while (0)

#define MFMA_PHASE() do { _Pragma("unroll") \
    for (int kk = 0; kk < 4; ++kk) { \
        short8 af[2], bf[2]; \
        _Pragma("unroll") \
        for (int i = 0; i < 2; ++i) \
            af[i] = *(const short8*)&sA[(wm + i * 16 + l15) * SASTR + kk * 32 + quad * 8]; \
        _Pragma("unroll") \
        for (int i = 0; i < 2; ++i) \
            bf[i] = *(const short8*)&sB[(wn + i * 16 + l15) * SASTR + kk * 32 + quad * 8]; \
        _Pragma("unroll") \
        for (int i = 0; i < 2; ++i) \
            _Pragma("unroll") \
            for (int j = 0; j < 2; ++j) \
                acc[i][j] = __builtin_amdgcn_mfma_f32_16x16x32_bf16(af[i], bf[j], acc[i][j], 0, 0, 0); \
    } } while (0)

// one GEMM phase: wait -> LDS write -> bar -> issue next -> MFMA -> bar
#define GP(AS, WS, CH2, VMN) do { \
    VMW(VMN); SCH0; \
    WRITE_AW(AS, WS); \
    LG0; BARR; \
    if ((CH2) > 0) ISSUE_AW(AS, WS, CH2); \
    MFMA_PHASE(); \
    BARR; } while (0)

    for (int t = 0; t < SEQ; ++t) {
        // ---------- issue order (in-order retire): [D,tau]  u(8)  w0(4)  B1(8) ----------
        f32x4 dv; float tv = 0.f;
        if (tid < 64 && t > 0) {
            gl4f_sc1(dv, D + ((t + 2) % 3) * 1024 + (size_t)(m0 + tid) * 4);
            gl1f(tv, tau + (size_t)(m0 + tid) * SEQ + (t - 1));
        }
        f32x4 u4[8];
#pragma unroll
        for (int i = 0; i < 4; ++i) {
#pragma unroll
            for (int j = 0; j < 2; ++j) {
                int s = 2 * (tid + i * 256) + j;
                gl4f(u4[i * 2 + j], rnn + ((size_t)(m0 + (s >> 5)) * SEQ + t) * INSZ + (s & 31) * 4);
            }
        }
        u32x4 w0[4];
#pragma unroll
        for (int i = 0; i < 4; ++i) {
            int s = tid + i * 256;
            gl4(w0[i], WpT + (size_t)(s >> 4) * 1152 + (s & 15) * 8);
        }
        u32x4 aA[4], wA[4], aB[4], wB[4];
        ISSUE_AW(aA, wA, 1);

        floatx4 acc[2][2];
        floatx4 z4 = {0.f, 0.f, 0.f, 0.f};
        acc[0][0] = z4; acc[0][1] = z4; acc[1][0] = z4; acc[1][1] = z4;

        // ---------- phase 0 (u chunk) ----------
        VMW("8"); SCH0;           // retires D,tau,u,w0; B1 (8) still in flight
        if (tid < 64) {
            if (t == 0) {
                sX[tid * 2] = xp0; sX[tid * 2 + 1] = xp1;
            } else {
                float al0 = sigf(dv[0] + ab0), al1 = sigf(dv[1] + ab1);
                float hx0 = dv[2] + hb0, hx1 = dv[3] + hb1;
                float xm0 = (1.f + 1.5f * tv) * xp0 - 1.5f * tv * xp1;
                float xm1 = (tv * (1.f / 1.5f)) * xp0 + xp1;
                float xn0 = al0 * xm0 + (1.f - al0) * hx0;
                float xn1 = al1 * xm1 + (1.f - al1) * hx1;
                xp0 = xn0; xp1 = xn1;
                sX[tid * 2] = xn0; sX[tid * 2 + 1] = xn1;
            }
        }
#pragma unroll
        for (int i = 0; i < 4; ++i) {
            int s = 2 * (tid + i * 256);
            int row = s >> 5, sc = s & 31;
            u32x4 pk;
            pk[0] = pack2(u4[2 * i][0], u4[2 * i][1]);
            pk[1] = pack2(u4[2 * i][2], u4[2 * i][3]);
            pk[2] = pack2(u4[2 * i + 1][0], u4[2 * i + 1][1]);
            pk[3] = pack2(u4[2 * i + 1][2], u4[2 * i + 1][3]);
            *(u32x4*)((char*)sA + row * (SASTR * 2) + sc * 8) = pk;
        }
#pragma unroll
        for (int i = 0; i < 4; ++i) {
            int s = tid + i * 256;
            *(u32x4*)((char*)sB + (s >> 4) * (SASTR * 2) + (s & 15) * 16) = w0[i];
        }
        LG0; BARR;
        ISSUE_AW(aB, wB, 2);
        MFMA_PHASE();
        BARR;

        // ---------- phases 1..8, depth-2 rotation ----------
        GP(aA, wA, 3, "8");
        GP(aB, wB, 4, "8");
        GP(aA, wA, 5, "8");
        GP(aB, wB, 6, "8");
        GP(aA, wA, 7, "8");
        GP(aB, wB, 8, "8");
        GP(aA, wA, 0, "8");
        GP(aB, wB, 0, "0");

        // ---------- exchange C through LDS ----------
#pragma unroll
        for (int i = 0; i < 2; ++i)
#pragma unroll
            for (int jx = 0; jx < 2; ++jx) {
                int row = wm + i * 16 + quad * 4, col = wn + jx * 16 + l15;
#pragma unroll
                for (int rr = 0; rr < 4; ++rr)
                    sC[(row + rr) * SCSTR + col] = acc[i][jx][rr];
            }
        LG0; BARR;

        // ---------- pointwise ----------
        float hv[4];
        float p0, p1, p2, p3;
        {
            float sx0, sx1;
#pragma unroll
            for (int i = 0; i < 4; ++i) {
                int m = (tid >> 4) + 16 * i;
                sx0 = sX[m * 2]; sx1 = sX[m * 2 + 1];
                float gi = bpv[0] + wxa[0] * sx0 + wxb[0] * sx1 + sC[m * SCSTR + 0 * 16 + jj];
                float gf = bpv[1] + wxa[1] * sx0 + wxb[1] * sx1 + sC[m * SCSTR + 1 * 16 + jj];
                float gg = bpv[2] + wxa[2] * sx0 + wxb[2] * sx1 + sC[m * SCSTR + 2 * 16 + jj];
                float go = bpv[3] + wxa[3] * sx0 + wxb[3] * sx1 + sC[m * SCSTR + 3 * 16 + jj];
                float cn = sigf(gf) * cr[i] + sigf(gi) * tanhf_(gg);
                float hn = sigf(go) * tanhf_(cn);
                cr[i] = cn;
                hv[i] = hn;
                int jgl = j0 + jj, mg = m0 + m;
                out[((size_t)mg * SEQ + t) * ZS + 2 + jgl] = hn;
                if (t == SEQ - 1) { zf[mg * ZS + 2 + jgl] = hn; czf[mg * ZS + 2 + jgl] = cn; }
                p0 = hn * aw0;  p1 = hn * aw1;
                p2 = hn * hw0;  p3 = hn * hw1;
#pragma unroll
                for (int o = 8; o > 0; o >>= 1) {
                    p0 += __shfl_down(p0, o, 16); p1 += __shfl_down(p1, o, 16);
                    p2 += __shfl_down(p2, o, 16); p3 += __shfl_down(p3, o, 16);
                }
                if ((tid & 15) == 0) {
                    float* Dp = D + (t % 3) * 1024 + mg * 4;
                    __hip_atomic_fetch_add(Dp + 0, p0, AL_RLX, SC_AGT);
                    __hip_atomic_fetch_add(Dp + 1, p1, AL_RLX, SC_AGT);
                    __hip_atomic_fetch_add(Dp + 2, p2, AL_RLX, SC_AGT);
                    __hip_atomic_fetch_add(Dp + 3, p3, AL_RLX, SC_AGT);
                }
            }
        }
        // deferred writer work (kept out of the counted GEMM region)
        if (writer) {
            float* Dz = D + ((t + 1) % 3) * 1024 + m0 * 4;
            __hip_atomic_store(Dz + tid, 0.f, AL_RLX, SC_AGT);
        }
        if (writer && tid < 64 && t > 0) {
            float* o = out + ((size_t)(m0 + tid) * SEQ + (t - 1)) * ZS;
            o[0] = xp0; o[1] = xp1;
        }
        // h -> Abuf (bf16, coherent) via sH
#pragma unroll
        for (int i = 0; i < 4; ++i) {
            int m = (tid >> 4) + 16 * i;
            sH[jj * 65 + m] = hv[i];
        }
        LG0; BARR;
#pragma unroll
        for (int i = 0; i < 2; ++i) {
            int dd = tid + i * 256;
            int m = dd >> 3, jp = dd & 7;
            u32 v = pack2(sH[(2 * jp) * 65 + m], sH[(2 * jp + 1) * 65 + m]);
            cstore(Abuf32 + (m0 + m) * 512 + jt * 8 + jp, v);
        }

        // ---------- per-mt tree barrier (full drain first: __syncthreads) ----------
        __syncthreads();
        if (tid == 0) {
            unsigned g = __hip_atomic_load(bgg, AL_RLX, SC_AGT);
            unsigned a = __hip_atomic_fetch_add(bcx, 1u, AL_REL, SC_AGT);
            if (a == 7u) {
                __hip_atomic_store(bcx, 0u, AL_RLX, SC_AGT);
                unsigned b = __hip_atomic_fetch_add(bcm, 1u, __ATOMIC_ACQ_REL, SC_AGT);
                if (b == 7u) {
                    __hip_atomic_store(bcm, 0u, AL_RLX, SC_AGT);
                    __hip_atomic_fetch_add(bgg, 1u, AL_REL, SC_AGT);
                }
            }
            while (__hip_atomic_load(bgg, AL_RLX, SC_AGT) == g)
                __builtin_amdgcn_s_sleep(2);
        }
        __syncthreads();
    }

    // ---------- final x-update (t = SEQ) + frozen cz columns ----------
    if (tid < 64) {
        int mg = m0 + tid;
        const float* Dp = D + ((SEQ - 1) % 3) * 1024 + mg * 4;
        float s0 = __hip_atomic_load(Dp + 0, AL_RLX, SC_AGT);
        float s1 = __hip_atomic_load(Dp + 1, AL_RLX, SC_AGT);
        float s2 = __hip_atomic_load(Dp + 2, AL_RLX, SC_AGT);
        float s3 = __hip_atomic_load(Dp + 3, AL_RLX, SC_AGT);
        float al0 = sigf(s0 + ab0), al1 = sigf(s1 + ab1);
        float hx0 = s2 + hb0, hx1 = s3 + hb1;
        float ta = tau[mg * SEQ + (SEQ - 1)];
        float xm0 = (1.f + 1.5f * ta) * xp0 - 1.5f * ta * xp1;
        float xm1 = (ta * (1.f / 1.5f)) * xp0 + xp1;
        float xn0 = al0 * xm0 + (1.f - al0) * hx0;
        float xn1 = al1 * xm1 + (1.f - al1) * hx1;
        if (writer) {
            float* o = out + ((size_t)mg * SEQ + (SEQ - 1)) * ZS;
            o[0] = xn0; o[1] = xn1;
            zf[mg * ZS + 0] = xn0; zf[mg * ZS + 1] = xn1;
            czf[mg * ZS + 0] = cz0[mg * ZS + 0];
            czf[mg * ZS + 1] = cz0[mg * ZS + 1];
        }
    }
#undef ISSUE_AW
#undef WRITE_AW
#undef MFMA_PHASE
#undef GP
}

extern "C" void kernel_launch(void* const* d_in, const int* in_sizes, int n_in,
                              void* d_out, int out_size, void* d_ws, size_t ws_size,
                              hipStream_t stream) {
    const float* rnn = (const float*)d_in[0];
    const float* tau = (const float*)d_in[1];
    const float* z0  = (const float*)d_in[2];
    const float* cz0 = (const float*)d_in[3];
    const float* WUw = (const float*)d_in[4];
    const float* WUb = (const float*)d_in[5];
    const float* aw  = (const float*)d_in[6];
    const float* ab  = (const float*)d_in[7];
    const float* hw  = (const float*)d_in[8];
    const float* hb  = (const float*)d_in[9];
    float* out = (float*)d_out;

    char* ws = (char*)d_ws;
    size_t off = 0;
    auto alloc = [&](size_t bytes) {
        void* p = ws + off;
        off += (bytes + 255) & ~(size_t)255;
        return p;
    };
    u16*   Wp     = (u16*)alloc((size_t)64 * 64 * 1152 * 2);   // 9.44 MB, jt-major
    u32*   Abuf32 = (u32*)alloc((size_t)BATCH * 512 * 4);      // 0.5 MB (h only)
    float* D      = (float*)alloc((size_t)3 * BATCH * 4 * 4);  // 12 KB
    float* bp     = (float*)alloc((size_t)4096 * 4);
    float* wxp    = (float*)alloc((size_t)8192 * 4);
    unsigned* bar_cnt = (unsigned*)alloc(256);
    unsigned* bar_gen = (unsigned*)alloc(256);
    unsigned* barX    = (unsigned*)alloc(32 * 64 * 4);   // 4mt x 8xcd, 256B stride
    unsigned* barM    = (unsigned*)alloc(4 * 64 * 4);    // per-mt combine
    unsigned* barG    = (unsigned*)alloc(4 * 64 * 4);    // per-mt generation

    hipMemsetAsync(bar_cnt, 0, 256 + 256 + 32 * 64 * 4 + 4 * 64 * 4 + 4 * 64 * 4, stream);

    hipLaunchKernelGGL(lstm_fused, dim3(NBLK), dim3(256), 0, stream,
                       rnn, tau, z0, cz0, WUw, WUb, aw, ab, hw, hb,
                       out, Wp, Abuf32, D, bp, wxp, bar_cnt, bar_gen,
                       barX, barM, barG);
}